// Round 6
// baseline (966.788 us; speedup 1.0000x reference)
//
#include <hip/hip_runtime.h>
#include <hip/hip_bf16.h>
#include <math.h>

#define NB   4
#define CIN  128
#define HH   96
#define WW   96
#define HWN  (HH*WW)        // 9216
#define NHW  (NB*HWN)       // 36864
#define COUT 128
#define KW   9
#define KDIM (CIN*KW)       // 1152
#define GSZ  16

typedef __attribute__((ext_vector_type(8))) short bf16x8;   // 8 bf16 (4 VGPRs)
typedef __attribute__((ext_vector_type(4))) float f32x4;    // 4 fp32 acc

// ws layout (float units)
#define OFF_WT    0          // 147456: wT[k][c][o] fp32
#define OFF_DX    147456
#define OFF_DY    184320
#define OFF_MASK  221184
#define OFF_GN    258048     // 128: s1[64], s2[64]
#define OFF_STATS 258176     // 64
#define OFF_MAP   258240     // 256 ints: D-layout map[lane*4+reg] = (m<<4)|n
#define OFF_PAIR  258496     // 32 ints: B-slot j must hold A-channel pairB[j]

__device__ __forceinline__ ushort f2bf(float f) {
    union { float f; uint u; } v; v.f = f;
    uint r = v.u + 0x7fffu + ((v.u >> 16) & 1u);   // RNE to bf16
    return (ushort)(r >> 16);
}
__device__ __forceinline__ float bf2f(ushort h) {
    union { uint u; float f; } v; v.u = ((uint)h) << 16;
    return v.f;
}

// ---------------------------------------------------------------- zero GN buf
__global__ void zero_gn(float* __restrict__ gn_part) {
    int t = threadIdx.x;
    if (t < 128) gn_part[t] = 0.f;
}

// ---------------------------------------------------- MFMA D-layout probe (r4-proven)
__global__ void mfma_probe(int* __restrict__ map) {
    int l = threadIdx.x;                 // one wave
    bf16x8 A1 = {}, B1 = {}, A2 = {}, B2 = {};
    if ((l >> 4) == 0) {
        A1[0] = (short)f2bf((float)((l & 15) + 1));
        B1[0] = (short)f2bf(1.0f);
        A2[0] = (short)f2bf(1.0f);
        B2[0] = (short)f2bf((float)((l & 15) + 1));
    }
    f32x4 d1 = {0.f,0.f,0.f,0.f}, d2 = {0.f,0.f,0.f,0.f};
    d1 = __builtin_amdgcn_mfma_f32_16x16x32_bf16(A1, B1, d1, 0, 0, 0);
    d2 = __builtin_amdgcn_mfma_f32_16x16x32_bf16(A2, B2, d2, 0, 0, 0);
#pragma unroll
    for (int r = 0; r < 4; ++r) {
        int m = (int)(d1[r] + 0.5f) - 1;
        int n = (int)(d2[r] + 0.5f) - 1;
        map[l * 4 + r] = (m << 4) | n;
    }
}

// ---------------------------------------------------- A/B k-slot pairing probe
// A-slot s=(lg,e): one-hot 1.0 on lanes of group lg at element e.
// B: every slot (lg',e') holds 2^(lg'*8+e') (exact powers of two).
// D is uniform = 2^(B-slot paired with A-slot s). pairB[j] = s means:
// B-slot j must carry the channel that A-slot s carries.
__global__ void pair_probe(int* __restrict__ pairB) {
    int l = threadIdx.x;                 // one wave
    union { bf16x8 v; short a[8]; } B;
#pragma unroll
    for (int e = 0; e < 8; ++e) {
        float val = (float)(1u << (((l >> 4) * 8 + e) & 31));
        B.a[e] = (short)f2bf(val);       // exact (power of 2)
    }
#pragma unroll
    for (int s = 0; s < 32; ++s) {
        union { bf16x8 v; short a[8]; } A;
#pragma unroll
        for (int e = 0; e < 8; ++e) A.a[e] = 0;
        if ((l >> 4) == (s >> 3)) A.a[s & 7] = (short)f2bf(1.0f);
        f32x4 d = {0.f, 0.f, 0.f, 0.f};
        d = __builtin_amdgcn_mfma_f32_16x16x32_bf16(A.v, B.v, d, 0, 0, 0);
        float v0 = d[0];
        if (l == 0 && v0 > 0.f) {
            int ex; frexpf(v0, &ex);     // v0 = 2^j -> ex = j+1
            int j = ex - 1;
            if (j >= 0 && j < 32) pairB[j] = s;
        }
    }
}

// ---------------------------------------------------------------- transpose (r2-proven)
__global__ __launch_bounds__(256) void transpose_w(const float* __restrict__ wd,
                                                   float* __restrict__ wT) {
    int i = blockIdx.x * 256 + threadIdx.x;      // < 147456
    int o = i & 127;
    int rest = i >> 7;                            // k*128 + c
    int c = rest & 127;
    int k = rest >> 7;
    wT[i] = wd[o * KDIM + c * KW + k];
}

// ---------------------------------------------------------------- head conv (r2-proven)
__global__ __launch_bounds__(256) void head_kernel(const float* __restrict__ x,
                                                   const float* __restrict__ w_head,
                                                   const float* __restrict__ b_head,
                                                   float* __restrict__ dxv,
                                                   float* __restrict__ dyv,
                                                   float* __restrict__ maskv) {
    __shared__ float wl[3456];    // wl[(c*9+kk)*3 + j]
    int t = threadIdx.x;
    for (int i = t; i < 3456; i += 256) {
        int j = i / KDIM, r = i - j * KDIM;       // r = c*9+kk
        wl[r * 3 + j] = w_head[i];
    }
    __syncthreads();

    int p = blockIdx.x * 256 + t;
    int n = p / HWN, hw = p % HWN;
    int h = hw / WW, w = hw % WW;

    int   offs[9];
    float msk[9];
#pragma unroll
    for (int ky = 0; ky < 3; ky++)
#pragma unroll
        for (int kx = 0; kx < 3; kx++) {
            int yy = h - 1 + ky, xx = w - 1 + kx;
            bool ok = (yy >= 0) && (yy < HH) && (xx >= 0) && (xx < WW);
            int yc = min(max(yy, 0), HH - 1), xc = min(max(xx, 0), WW - 1);
            offs[ky * 3 + kx] = yc * WW + xc;
            msk[ky * 3 + kx] = ok ? 1.f : 0.f;
        }

    float a0 = b_head[0], a1 = b_head[1], a2 = b_head[2];
    const float* xn = x + (size_t)n * CIN * HWN;
    for (int c = 0; c < CIN; c++) {
        const float* xc = xn + c * HWN;
        const float* wc = &wl[c * 27];
#pragma unroll
        for (int kk = 0; kk < 9; kk++) {
            float v = xc[offs[kk]] * msk[kk];
            a0 = fmaf(v, wc[kk * 3 + 0], a0);
            a1 = fmaf(v, wc[kk * 3 + 1], a1);
            a2 = fmaf(v, wc[kk * 3 + 2], a2);
        }
    }
    dxv[p]   = 0.25f * tanhf(a0);
    dyv[p]   = 0.25f * tanhf(a1);
    maskv[p] = 1.f / (1.f + expf(-a2));
}

// ---------------------------------------------------------------- main DCN (DUAL PATH)
// r2-proven fp32 FMA path drives output + GN. Pairing-corrected hi/lo MFMA path
// is cross-checked against it; any >0.01 disagreement adds +100 to all stores.
__global__ __launch_bounds__(256) void dcn_kernel(const float* __restrict__ x,
                                                  const float* __restrict__ wT,
                                                  const float* __restrict__ dxv,
                                                  const float* __restrict__ dyv,
                                                  const float* __restrict__ maskv,
                                                  const int* __restrict__ map,
                                                  const int* __restrict__ pairB,
                                                  float* __restrict__ out,
                                                  float* __restrict__ gn_part) {
    __shared__ float sW[32 * 128];     // [c][o] 16 KB
    __shared__ float sS[32 * 64];      // [c][pix] 8 KB
    __shared__ float sY[128 * 64];     // cross-check tile 32 KB
    __shared__ int   sAddr[64 * 4];
    __shared__ float sWgt[64 * 4];
    __shared__ float sMask[64];
    __shared__ float gred[16];
    __shared__ int   sFlag;

    const int t = threadIdx.x;
    const int lane = t & 63;
    const int wv = t >> 6;

    const int p0  = blockIdx.x * 64;
    const int n   = p0 / HWN;
    const int hw0 = p0 % HWN;
    const float* xn = x + (size_t)n * CIN * HWN;

    if (t < 64) sMask[t] = maskv[p0 + t];
    if (t < 16) gred[t] = 0.f;
    if (t == 0) sFlag = 0;

    float dxl = 0.f, dyl = 0.f;
    int hme = 0, wme = 0;
    if (t < 64) {
        dxl = dxv[p0 + t]; dyl = dyv[p0 + t];
        int hw = hw0 + t; hme = hw / WW; wme = hw % WW;
    }

    // FMA path accumulators (r2)
    const int ow = t & 31, pg = t >> 5, o0 = ow * 4;
    float accf[4][8];
#pragma unroll
    for (int i = 0; i < 4; i++)
#pragma unroll
        for (int j = 0; j < 8; j++) accf[i][j] = 0.f;

    // MFMA path accumulators + pairing table for this lane's 8 B-slots
    f32x4 accm[2][4];
#pragma unroll
    for (int i = 0; i < 2; i++)
#pragma unroll
        for (int j = 0; j < 4; j++) accm[i][j] = (f32x4){0.f, 0.f, 0.f, 0.f};
    int cB[8];
#pragma unroll
    for (int e = 0; e < 8; ++e) cB[e] = pairB[(lane >> 4) * 8 + e] & 31;

    const int oyc[9] = {0, 0, 0, 1, 0, -1, 1, 1, -1};
    const int oxc[9] = {0, 1, -1, 0, 0, 0, 1, -1, 1};

    for (int k = 0; k < 9; ++k) {
        __syncthreads();   // A
        if (t < 64) {
            int ky = k / 3, kx = k - ky * 3;
            float py = (float)(hme - 1 + ky) + (float)oyc[k] * dxl;
            float px = (float)(wme - 1 + kx) + (float)oxc[k] * dyl;
            float fy0 = floorf(py), fx0 = floorf(px);
            int y0 = (int)fy0, x0 = (int)fx0;
            float fy = py - fy0, fx = px - fx0;
#pragma unroll
            for (int j = 0; j < 4; ++j) {
                int yy = y0 + (j >> 1), xx = x0 + (j & 1);
                float wb = ((j >> 1) ? fy : 1.f - fy) * ((j & 1) ? fx : 1.f - fx);
                bool ok = (yy >= 0) && (yy < HH) && (xx >= 0) && (xx < WW);
                int yc = min(max(yy, 0), HH - 1), xc = min(max(xx, 0), WW - 1);
                sAddr[t * 4 + j] = yc * WW + xc;
                sWgt[t * 4 + j] = ok ? wb : 0.f;
            }
        }
        __syncthreads();   // B

        for (int cc = 0; cc < CIN; cc += 32) {
            const float4* wsrc = (const float4*)(wT + ((k * CIN + cc) << 7));
            float4* wdst = (float4*)sW;
#pragma unroll
            for (int i = 0; i < 4; i++) wdst[t + (i << 8)] = wsrc[t + (i << 8)];
#pragma unroll
            for (int i = 0; i < 8; i++) {
                int idx = t + (i << 8);
                int c = idx >> 6, pix = idx & 63;
                const float* xc = xn + (size_t)(cc + c) * HWN;
                float s = xc[sAddr[pix * 4 + 0]] * sWgt[pix * 4 + 0]
                        + xc[sAddr[pix * 4 + 1]] * sWgt[pix * 4 + 1]
                        + xc[sAddr[pix * 4 + 2]] * sWgt[pix * 4 + 2]
                        + xc[sAddr[pix * 4 + 3]] * sWgt[pix * 4 + 3];
                sS[c * 64 + pix] = s;
            }
            __syncthreads();   // C

            // ---------- FMA path (r2-verbatim)
#pragma unroll
            for (int c = 0; c < 32; ++c) {
                float4 a  = *(const float4*)&sW[c * 128 + o0];
                float4 b0 = *(const float4*)&sS[c * 64 + pg * 8];
                float4 b1 = *(const float4*)&sS[c * 64 + pg * 8 + 4];
                float av[4] = {a.x, a.y, a.z, a.w};
                float bv[8] = {b0.x, b0.y, b0.z, b0.w, b1.x, b1.y, b1.z, b1.w};
#pragma unroll
                for (int i = 0; i < 4; i++)
#pragma unroll
                    for (int j = 0; j < 8; j++) accf[i][j] = fmaf(av[i], bv[j], accf[i][j]);
            }

            // ---------- MFMA path: hi/lo split, pairing-corrected B pack
            const int g8 = (lane >> 4) * 8;
            const int ml = lane & 15;
            bf16x8 Ah0, Al0, Ah1, Al1;
#pragma unroll
            for (int e = 0; e < 8; ++e) {
                float w0 = sW[(g8 + e) * 128 + wv * 32 + ml];
                ushort h0 = f2bf(w0);
                Ah0[e] = (short)h0; Al0[e] = (short)f2bf(w0 - bf2f(h0));
                float w1 = sW[(g8 + e) * 128 + wv * 32 + 16 + ml];
                ushort h1 = f2bf(w1);
                Ah1[e] = (short)h1; Al1[e] = (short)f2bf(w1 - bf2f(h1));
            }
#pragma unroll
            for (int pt = 0; pt < 4; ++pt) {
                bf16x8 Bh, Bl;
#pragma unroll
                for (int e = 0; e < 8; ++e) {
                    float sv = sS[cB[e] * 64 + pt * 16 + ml];
                    ushort h = f2bf(sv);
                    Bh[e] = (short)h; Bl[e] = (short)f2bf(sv - bf2f(h));
                }
                accm[0][pt] = __builtin_amdgcn_mfma_f32_16x16x32_bf16(Ah0, Bh, accm[0][pt], 0, 0, 0);
                accm[0][pt] = __builtin_amdgcn_mfma_f32_16x16x32_bf16(Ah0, Bl, accm[0][pt], 0, 0, 0);
                accm[0][pt] = __builtin_amdgcn_mfma_f32_16x16x32_bf16(Al0, Bh, accm[0][pt], 0, 0, 0);
                accm[1][pt] = __builtin_amdgcn_mfma_f32_16x16x32_bf16(Ah1, Bh, accm[1][pt], 0, 0, 0);
                accm[1][pt] = __builtin_amdgcn_mfma_f32_16x16x32_bf16(Ah1, Bl, accm[1][pt], 0, 0, 0);
                accm[1][pt] = __builtin_amdgcn_mfma_f32_16x16x32_bf16(Al1, Bh, accm[1][pt], 0, 0, 0);
            }
            __syncthreads();   // D
        }
    }

    // ---- cross-check MFMA vs FMA through LDS
#pragma unroll
    for (int i = 0; i < 4; i++)
#pragma unroll
        for (int j = 0; j < 8; j++) sY[(o0 + i) * 64 + pg * 8 + j] = accf[i][j];
    __syncthreads();

    int4 mn4 = *(const int4*)&map[lane * 4];
    int mn[4] = {mn4.x, mn4.y, mn4.z, mn4.w};
    int flag = 0;
#pragma unroll
    for (int ot = 0; ot < 2; ++ot)
#pragma unroll
        for (int pt = 0; pt < 4; ++pt)
#pragma unroll
            for (int r = 0; r < 4; ++r) {
                int m = mn[r] >> 4, nn = mn[r] & 15;
                float ref = sY[(wv * 32 + ot * 16 + m) * 64 + pt * 16 + nn];
                if (fabsf(accm[ot][pt][r] - ref) > 0.01f) flag = 1;
            }
    if (flag) atomicOr(&sFlag, 1);
    __syncthreads();
    float corrupt = sFlag ? 100.f : 0.f;

    // ---- r2-verbatim epilogue from the FMA path (plus corruption marker)
    float mm[8];
#pragma unroll
    for (int j = 0; j < 8; j++) mm[j] = sMask[pg * 8 + j];
    float s1 = 0.f, s2 = 0.f;
#pragma unroll
    for (int i = 0; i < 4; i++) {
        float v[8];
#pragma unroll
        for (int j = 0; j < 8; j++) {
            v[j] = accf[i][j] * mm[j];
            s1 += v[j];
            s2 += v[j] * v[j];
        }
        float* dst = out + ((size_t)(n * COUT) + (o0 + i)) * HWN + hw0 + pg * 8;
        *(float4*)dst       = make_float4(v[0] + corrupt, v[1] + corrupt, v[2] + corrupt, v[3] + corrupt);
        *(float4*)(dst + 4) = make_float4(v[4] + corrupt, v[5] + corrupt, v[6] + corrupt, v[7] + corrupt);
    }
    int g = o0 >> 4;
    atomicAdd(&gred[g * 2 + 0], s1);
    atomicAdd(&gred[g * 2 + 1], s2);
    __syncthreads();
    if (t < 8) {
        atomicAdd(&gn_part[n * 8 + t],      gred[t * 2 + 0]);
        atomicAdd(&gn_part[64 + n * 8 + t], gred[t * 2 + 1]);
    }
}

// ---------------------------------------------------------------- GN stats
__global__ void gn_stats(const float* __restrict__ gn_part, float* __restrict__ stats) {
    int i = threadIdx.x;
    if (i < 32) {
        float cnt = (float)GSZ * (float)HWN;
        float s1 = gn_part[i], s2 = gn_part[64 + i];
        float mu = s1 / cnt;
        float var = s2 / cnt - mu * mu;
        stats[i] = mu;
        stats[32 + i] = rsqrtf(var + 1e-5f);
    }
}

// ---------------------------------------------------------------- GN apply
__global__ __launch_bounds__(256) void gn_apply(float* __restrict__ out,
                                                const float* __restrict__ stats,
                                                const float* __restrict__ gamma,
                                                const float* __restrict__ beta) {
    int i4 = blockIdx.x * 256 + threadIdx.x;
    size_t e = (size_t)i4 * 4;
    int og = (int)(e / HWN);
    int n = og >> 7, o = og & 127;
    int s = n * 8 + (o >> 4);
    float mu = stats[s], inv = stats[32 + s];
    float ga = gamma[o] * inv;
    float be = beta[o] - mu * ga;
    float4 v = *(float4*)(out + e);
    v.x = fmaxf(fmaf(v.x, ga, be), 0.f);
    v.y = fmaxf(fmaf(v.y, ga, be), 0.f);
    v.z = fmaxf(fmaf(v.z, ga, be), 0.f);
    v.w = fmaxf(fmaf(v.w, ga, be), 0.f);
    *(float4*)(out + e) = v;
}

// ---------------------------------------------------------------- launch
extern "C" void kernel_launch(void* const* d_in, const int* in_sizes, int n_in,
                              void* d_out, int out_size, void* d_ws, size_t ws_size,
                              hipStream_t stream) {
    const float* x       = (const float*)d_in[0];
    const float* w_head  = (const float*)d_in[1];
    const float* b_head  = (const float*)d_in[2];
    const float* w_dcn   = (const float*)d_in[3];
    const float* gamma   = (const float*)d_in[4];
    const float* beta    = (const float*)d_in[5];
    float* out = (float*)d_out;
    float* ws  = (float*)d_ws;

    float* wT      = ws + OFF_WT;
    float* dxv     = ws + OFF_DX;
    float* dyv     = ws + OFF_DY;
    float* maskv   = ws + OFF_MASK;
    float* gn_part = ws + OFF_GN;
    float* stats   = ws + OFF_STATS;
    int*   map     = (int*)(ws + OFF_MAP);
    int*   pairB   = (int*)(ws + OFF_PAIR);

    zero_gn<<<1, 128, 0, stream>>>(gn_part);
    mfma_probe<<<1, 64, 0, stream>>>(map);
    pair_probe<<<1, 64, 0, stream>>>(pairB);
    transpose_w<<<147456 / 256, 256, 0, stream>>>(w_dcn, wT);
    head_kernel<<<NHW / 256, 256, 0, stream>>>(x, w_head, b_head, dxv, dyv, maskv);
    dcn_kernel<<<NHW / 64, 256, 0, stream>>>(x, wT, dxv, dyv, maskv, map, pairB, out, gn_part);
    gn_stats<<<1, 64, 0, stream>>>(gn_part, stats);
    gn_apply<<<(NB * COUT * HWN) / 4 / 256, 256, 0, stream>>>(out, stats, gamma, beta);
}

// Round 7
// 305.321 us; speedup vs baseline: 3.1665x; 3.1665x over previous
//
#include <hip/hip_runtime.h>
#include <hip/hip_bf16.h>
#include <math.h>

#define NB   4
#define CIN  128
#define HH   96
#define WW   96
#define HWN  (HH*WW)        // 9216
#define NHW  (NB*HWN)       // 36864
#define COUT 128
#define KW   9
#define KDIM (CIN*KW)       // 1152
#define GSZ  16
#define ROW  40             // sB row stride in ushorts (80B, 16B-aligned rows)

typedef __attribute__((ext_vector_type(8))) short bf16x8;   // 8 bf16 (4 VGPRs)
typedef __attribute__((ext_vector_type(4))) float f32x4;    // 4 fp32 acc

// ws layout (float units)
#define OFF_WAH   0          // 73728 floats = 147456 ushorts: W hi, A-frag identity order
#define OFF_WAL   73728      // W lo
#define OFF_DX    147456
#define OFF_DY    184320
#define OFF_MASK  221184
#define OFF_GN    258048     // 128: s1[64], s2[64]
#define OFF_STATS 258176     // 64
#define OFF_MAP   258240     // 256 ints: D-layout map[lane*4+reg] = (m<<4)|n
#define OFF_PAIR  258496     // 32 ints: B-slot j holds A-channel pairB[j]
#define OFF_POS   258528     // 32 ints: posB[c] = slot for channel c (inverse)

__device__ __forceinline__ ushort f2bf(float f) {
    union { float f; uint u; } v; v.f = f;
    uint r = v.u + 0x7fffu + ((v.u >> 16) & 1u);   // RNE to bf16
    return (ushort)(r >> 16);
}
__device__ __forceinline__ float bf2f(ushort h) {
    union { uint u; float f; } v; v.u = ((uint)h) << 16;
    return v.f;
}

// ---------------------------------------------------------------- zero GN buf
__global__ void zero_gn(float* __restrict__ gn_part) {
    int t = threadIdx.x;
    if (t < 128) gn_part[t] = 0.f;
}

// ---------------------------------------------------- MFMA D-layout probe (HW-verified r4/r6)
__global__ void mfma_probe(int* __restrict__ map) {
    int l = threadIdx.x;                 // one wave
    bf16x8 A1 = {}, B1 = {}, A2 = {}, B2 = {};
    if ((l >> 4) == 0) {
        A1[0] = (short)f2bf((float)((l & 15) + 1));
        B1[0] = (short)f2bf(1.0f);
        A2[0] = (short)f2bf(1.0f);
        B2[0] = (short)f2bf((float)((l & 15) + 1));
    }
    f32x4 d1 = {0.f,0.f,0.f,0.f}, d2 = {0.f,0.f,0.f,0.f};
    d1 = __builtin_amdgcn_mfma_f32_16x16x32_bf16(A1, B1, d1, 0, 0, 0);
    d2 = __builtin_amdgcn_mfma_f32_16x16x32_bf16(A2, B2, d2, 0, 0, 0);
#pragma unroll
    for (int r = 0; r < 4; ++r) {
        int m = (int)(d1[r] + 0.5f) - 1;
        int n = (int)(d2[r] + 0.5f) - 1;
        map[l * 4 + r] = (m << 4) | n;
    }
}

// ---------------------------------------------------- A/B k-slot pairing probe (HW-verified r6)
// pairB[j] = s : B-slot j multiplies with A-slot s.  posB[s] = j (inverse).
__global__ void pair_probe(int* __restrict__ pairB, int* __restrict__ posB) {
    int l = threadIdx.x;                 // one wave
    union { bf16x8 v; short a[8]; } B;
#pragma unroll
    for (int e = 0; e < 8; ++e) {
        float val = (float)(1u << (((l >> 4) * 8 + e) & 31));
        B.a[e] = (short)f2bf(val);       // exact powers of two
    }
#pragma unroll
    for (int s = 0; s < 32; ++s) {
        union { bf16x8 v; short a[8]; } A;
#pragma unroll
        for (int e = 0; e < 8; ++e) A.a[e] = 0;
        if ((l >> 4) == (s >> 3)) A.a[s & 7] = (short)f2bf(1.0f);
        f32x4 d = {0.f, 0.f, 0.f, 0.f};
        d = __builtin_amdgcn_mfma_f32_16x16x32_bf16(A.v, B.v, d, 0, 0, 0);
        float v0 = d[0];
        if (l == 0 && v0 > 0.f) {
            int ex; frexpf(v0, &ex);     // v0 = 2^j -> ex = j+1
            int j = ex - 1;
            if (j >= 0 && j < 32) { pairB[j] = s; posB[s] = j; }
        }
    }
}

// ------------------------------------------------- W split, A-frag identity order
// wa[((k*4+q)*8 + ot)*512 + l*8 + e] = W[o=ot*16+(l&15)][c=q*32+(l>>4)*8+e][tap k]
// (identity A-side slot->channel map — exactly what r6's verified A-pack used)
__global__ __launch_bounds__(256) void wsplit(const float* __restrict__ wd,
                                              ushort* __restrict__ wah,
                                              ushort* __restrict__ wal) {
    int i = blockIdx.x * 256 + threadIdx.x;       // < 147456
    int e  = i & 7;
    int l  = (i >> 3) & 63;
    int ot = (i >> 9) & 7;
    int q  = (i >> 12) & 3;
    int k  = i >> 14;                             // 0..8
    int o  = ot * 16 + (l & 15);
    int c  = q * 32 + (l >> 4) * 8 + e;
    float w = wd[o * KDIM + c * KW + k];
    ushort h = f2bf(w);
    wah[i] = h;
    wal[i] = f2bf(w - bf2f(h));
}

// ---------------------------------------------------------------- head conv (r2-proven)
__global__ __launch_bounds__(256) void head_kernel(const float* __restrict__ x,
                                                   const float* __restrict__ w_head,
                                                   const float* __restrict__ b_head,
                                                   float* __restrict__ dxv,
                                                   float* __restrict__ dyv,
                                                   float* __restrict__ maskv) {
    __shared__ float wl[3456];    // wl[(c*9+kk)*3 + j]
    int t = threadIdx.x;
    for (int i = t; i < 3456; i += 256) {
        int j = i / KDIM, r = i - j * KDIM;       // r = c*9+kk
        wl[r * 3 + j] = w_head[i];
    }
    __syncthreads();

    int p = blockIdx.x * 256 + t;
    int n = p / HWN, hw = p % HWN;
    int h = hw / WW, w = hw % WW;

    int   offs[9];
    float msk[9];
#pragma unroll
    for (int ky = 0; ky < 3; ky++)
#pragma unroll
        for (int kx = 0; kx < 3; kx++) {
            int yy = h - 1 + ky, xx = w - 1 + kx;
            bool ok = (yy >= 0) && (yy < HH) && (xx >= 0) && (xx < WW);
            int yc = min(max(yy, 0), HH - 1), xc = min(max(xx, 0), WW - 1);
            offs[ky * 3 + kx] = yc * WW + xc;
            msk[ky * 3 + kx] = ok ? 1.f : 0.f;
        }

    float a0 = b_head[0], a1 = b_head[1], a2 = b_head[2];
    const float* xn = x + (size_t)n * CIN * HWN;
    for (int c = 0; c < CIN; c++) {
        const float* xc = xn + c * HWN;
        const float* wc = &wl[c * 27];
#pragma unroll
        for (int kk = 0; kk < 9; kk++) {
            float v = xc[offs[kk]] * msk[kk];
            a0 = fmaf(v, wc[kk * 3 + 0], a0);
            a1 = fmaf(v, wc[kk * 3 + 1], a1);
            a2 = fmaf(v, wc[kk * 3 + 2], a2);
        }
    }
    dxv[p]   = 0.25f * tanhf(a0);
    dyv[p]   = 0.25f * tanhf(a1);
    maskv[p] = 1.f / (1.f + expf(-a2));
}

// ---------------------------------------------------------------- main DCN (clean MFMA)
// Block: 128 o x 64 px, 4 waves. Sampler writes bf16 hi/lo straight into LDS in
// B-fragment order (posB pairing-corrected, double-buffered). A frags from global
// (pre-split, identity order). 24 MFMAs/chunk (hi*hi + hi*lo + lo*hi).
__global__ __launch_bounds__(256) void dcn_kernel(const float* __restrict__ x,
                                                  const ushort* __restrict__ wah,
                                                  const ushort* __restrict__ wal,
                                                  const float* __restrict__ dxv,
                                                  const float* __restrict__ dyv,
                                                  const float* __restrict__ maskv,
                                                  const int* __restrict__ map,
                                                  const int* __restrict__ posB,
                                                  float* __restrict__ out,
                                                  float* __restrict__ gn_part) {
    __shared__ __attribute__((aligned(16))) ushort sBh[2 * 64 * ROW];  // 10 KB
    __shared__ __attribute__((aligned(16))) ushort sBl[2 * 64 * ROW];  // 10 KB
    __shared__ int   sAddr[64 * 4];
    __shared__ float sWgt[64 * 4];
    __shared__ float sMask[64];
    __shared__ float gred[16];

    const int t = threadIdx.x;
    const int lane = t & 63;
    const int wv = t >> 6;
    const int lg = lane >> 4;      // k-lane-group 0..3
    const int ml = lane & 15;

    // XCD swizzle: each XCD owns a contiguous half-image slab (L2-resident x)
    int b = blockIdx.x;
    int nb = (b & 7) * 72 + (b >> 3);
    const int p0  = nb * 64;
    const int n   = p0 / HWN;
    const int hw0 = p0 % HWN;
    const float* xn = x + (size_t)n * CIN * HWN;

    if (t < 64) sMask[t] = maskv[p0 + t];
    if (t < 16) gred[t] = 0.f;

    float dxl = 0.f, dyl = 0.f;
    int hme = 0, wme = 0;
    if (t < 64) {
        dxl = dxv[p0 + t]; dyl = dyv[p0 + t];
        int hw = hw0 + t; hme = hw / WW; wme = hw % WW;
    }

    // my 8 channel slots (channel c = wv + 4i within a 32-chunk)
    int myPos[8];
#pragma unroll
    for (int i = 0; i < 8; ++i) myPos[i] = posB[wv + 4 * i] & 31;

    f32x4 acc[2][4];
#pragma unroll
    for (int i = 0; i < 2; i++)
#pragma unroll
        for (int j = 0; j < 4; j++) acc[i][j] = (f32x4){0.f, 0.f, 0.f, 0.f};

    const int oyc[9] = {0, 0, 0, 1, 0, -1, 1, 1, -1};
    const int oxc[9] = {0, 1, -1, 0, 0, 0, 1, -1, 1};

    const int pix = t & 63;

    for (int k = 0; k < 9; ++k) {
        if (t < 64) {
            int ky = k / 3, kx = k - ky * 3;
            float py = (float)(hme - 1 + ky) + (float)oyc[k] * dxl;
            float px = (float)(wme - 1 + kx) + (float)oxc[k] * dyl;
            float fy0 = floorf(py), fx0 = floorf(px);
            int y0 = (int)fy0, x0 = (int)fx0;
            float fy = py - fy0, fx = px - fx0;
#pragma unroll
            for (int j = 0; j < 4; ++j) {
                int yy = y0 + (j >> 1), xx = x0 + (j & 1);
                float wb = ((j >> 1) ? fy : 1.f - fy) * ((j & 1) ? fx : 1.f - fx);
                bool ok = (yy >= 0) && (yy < HH) && (xx >= 0) && (xx < WW);
                int yc = min(max(yy, 0), HH - 1), xc = min(max(xx, 0), WW - 1);
                sAddr[t * 4 + j] = yc * WW + xc;
                sWgt[t * 4 + j] = ok ? wb : 0.f;
            }
        }
        __syncthreads();   // sAddr/sWgt ready (also orders prev-tap sB reads vs reuse)
        int4   ai = *(const int4*)&sAddr[pix * 4];
        float4 wq = *(const float4*)&sWgt[pix * 4];

        for (int q = 0; q < 4; ++q) {
            const int cc = q * 32;
            ushort* bufh = &sBh[(q & 1) * 64 * ROW];
            ushort* bufl = &sBl[(q & 1) * 64 * ROW];
            // ---- sample 8 channels for my pixel, write B-frag slots directly
#pragma unroll
            for (int i = 0; i < 8; ++i) {
                int c = wv + 4 * i;
                const float* xc = xn + (size_t)(cc + c) * HWN;
                float s = xc[ai.x] * wq.x + xc[ai.y] * wq.y
                        + xc[ai.z] * wq.z + xc[ai.w] * wq.w;
                ushort h = f2bf(s);
                bufh[pix * ROW + myPos[i]] = h;
                bufl[pix * ROW + myPos[i]] = f2bf(s - bf2f(h));
            }
            // ---- A fragments from global (L2-resident, identity slot order)
            const size_t abase = (size_t)((k * 4 + q) * 8 + wv * 2) * 512 + lane * 8;
            bf16x8 Ah0 = *(const bf16x8*)(wah + abase);
            bf16x8 Ah1 = *(const bf16x8*)(wah + abase + 512);
            bf16x8 Al0 = *(const bf16x8*)(wal + abase);
            bf16x8 Al1 = *(const bf16x8*)(wal + abase + 512);
            __syncthreads();   // sB ready
            // ---- B frags (ds_read_b128) + 24 MFMAs
#pragma unroll
            for (int pt = 0; pt < 4; ++pt) {
                const int rbase = (pt * 16 + ml) * ROW + lg * 8;
                bf16x8 Bh = *(const bf16x8*)&bufh[rbase];
                bf16x8 Bl = *(const bf16x8*)&bufl[rbase];
                acc[0][pt] = __builtin_amdgcn_mfma_f32_16x16x32_bf16(Ah0, Bh, acc[0][pt], 0, 0, 0);
                acc[0][pt] = __builtin_amdgcn_mfma_f32_16x16x32_bf16(Ah0, Bl, acc[0][pt], 0, 0, 0);
                acc[0][pt] = __builtin_amdgcn_mfma_f32_16x16x32_bf16(Al0, Bh, acc[0][pt], 0, 0, 0);
                acc[1][pt] = __builtin_amdgcn_mfma_f32_16x16x32_bf16(Ah1, Bh, acc[1][pt], 0, 0, 0);
                acc[1][pt] = __builtin_amdgcn_mfma_f32_16x16x32_bf16(Ah1, Bl, acc[1][pt], 0, 0, 0);
                acc[1][pt] = __builtin_amdgcn_mfma_f32_16x16x32_bf16(Al1, Bh, acc[1][pt], 0, 0, 0);
            }
        }
    }

    // ---- epilogue: mask, scatter via probed D layout, GN partials
    int4 mn4 = *(const int4*)&map[lane * 4];
    int mn[4] = {mn4.x, mn4.y, mn4.z, mn4.w};
    float s1g[2] = {0.f, 0.f}, s2g[2] = {0.f, 0.f};
#pragma unroll
    for (int ot = 0; ot < 2; ++ot) {
        int otile = wv * 32 + ot * 16;
#pragma unroll
        for (int pt = 0; pt < 4; ++pt) {
#pragma unroll
            for (int r = 0; r < 4; ++r) {
                int m = mn[r] >> 4, nn2 = mn[r] & 15;
                int p = pt * 16 + nn2;
                float v = acc[ot][pt][r] * sMask[p];
                s1g[ot] += v;
                s2g[ot] += v * v;
                out[((size_t)n * COUT + otile + m) * HWN + hw0 + p] = v;
            }
        }
    }
#pragma unroll
    for (int ot = 0; ot < 2; ++ot) {
        int g = wv * 2 + ot;
        atomicAdd(&gred[g * 2 + 0], s1g[ot]);
        atomicAdd(&gred[g * 2 + 1], s2g[ot]);
    }
    __syncthreads();
    if (t < 8) {
        atomicAdd(&gn_part[n * 8 + t],      gred[t * 2 + 0]);
        atomicAdd(&gn_part[64 + n * 8 + t], gred[t * 2 + 1]);
    }
}

// ---------------------------------------------------------------- GN stats
__global__ void gn_stats(const float* __restrict__ gn_part, float* __restrict__ stats) {
    int i = threadIdx.x;
    if (i < 32) {
        float cnt = (float)GSZ * (float)HWN;
        float s1 = gn_part[i], s2 = gn_part[64 + i];
        float mu = s1 / cnt;
        float var = s2 / cnt - mu * mu;
        stats[i] = mu;
        stats[32 + i] = rsqrtf(var + 1e-5f);
    }
}

// ---------------------------------------------------------------- GN apply
__global__ __launch_bounds__(256) void gn_apply(float* __restrict__ out,
                                                const float* __restrict__ stats,
                                                const float* __restrict__ gamma,
                                                const float* __restrict__ beta) {
    int i4 = blockIdx.x * 256 + threadIdx.x;
    size_t e = (size_t)i4 * 4;
    int og = (int)(e / HWN);
    int n = og >> 7, o = og & 127;
    int s = n * 8 + (o >> 4);
    float mu = stats[s], inv = stats[32 + s];
    float ga = gamma[o] * inv;
    float be = beta[o] - mu * ga;
    float4 v = *(float4*)(out + e);
    v.x = fmaxf(fmaf(v.x, ga, be), 0.f);
    v.y = fmaxf(fmaf(v.y, ga, be), 0.f);
    v.z = fmaxf(fmaf(v.z, ga, be), 0.f);
    v.w = fmaxf(fmaf(v.w, ga, be), 0.f);
    *(float4*)(out + e) = v;
}

// ---------------------------------------------------------------- launch
extern "C" void kernel_launch(void* const* d_in, const int* in_sizes, int n_in,
                              void* d_out, int out_size, void* d_ws, size_t ws_size,
                              hipStream_t stream) {
    const float* x       = (const float*)d_in[0];
    const float* w_head  = (const float*)d_in[1];
    const float* b_head  = (const float*)d_in[2];
    const float* w_dcn   = (const float*)d_in[3];
    const float* gamma   = (const float*)d_in[4];
    const float* beta    = (const float*)d_in[5];
    float* out = (float*)d_out;
    float* ws  = (float*)d_ws;

    ushort* wah    = (ushort*)(ws + OFF_WAH);
    ushort* wal    = (ushort*)(ws + OFF_WAL);
    float* dxv     = ws + OFF_DX;
    float* dyv     = ws + OFF_DY;
    float* maskv   = ws + OFF_MASK;
    float* gn_part = ws + OFF_GN;
    float* stats   = ws + OFF_STATS;
    int*   map     = (int*)(ws + OFF_MAP);
    int*   pairB   = (int*)(ws + OFF_PAIR);
    int*   posB    = (int*)(ws + OFF_POS);

    zero_gn<<<1, 128, 0, stream>>>(gn_part);
    mfma_probe<<<1, 64, 0, stream>>>(map);
    pair_probe<<<1, 64, 0, stream>>>(pairB, posB);
    wsplit<<<147456 / 256, 256, 0, stream>>>(w_dcn, wah, wal);
    head_kernel<<<NHW / 256, 256, 0, stream>>>(x, w_head, b_head, dxv, dyv, maskv);
    dcn_kernel<<<NHW / 64, 256, 0, stream>>>(x, wah, wal, dxv, dyv, maskv, map, posB, out, gn_part);
    gn_stats<<<1, 64, 0, stream>>>(gn_part, stats);
    gn_apply<<<(NB * COUT * HWN) / 4 / 256, 256, 0, stream>>>(out, stats, gamma, beta);
}

// Round 8
// 203.772 us; speedup vs baseline: 4.7445x; 1.4983x over previous
//
#include <hip/hip_runtime.h>
#include <hip/hip_bf16.h>
#include <math.h>

#define NB   4
#define CIN  128
#define HH   96
#define WW   96
#define HWN  (HH*WW)        // 9216
#define NHW  (NB*HWN)       // 36864
#define COUT 128
#define KW   9
#define KDIM (CIN*KW)       // 1152
#define GSZ  16
#define PXB  32             // pixels per dcn block
#define NBLK (NHW/PXB)      // 1152

typedef __attribute__((ext_vector_type(8))) short bf16x8;   // 8 bf16 (4 VGPRs)
typedef __attribute__((ext_vector_type(4))) float f32x4;    // 4 fp32 acc

// ws layout (float units)
#define OFF_WAH   0          // 73728 floats = 147456 ushorts: W hi, A-frag identity order
#define OFF_WAL   73728      // W lo
#define OFF_DX    147456
#define OFF_DY    184320
#define OFF_MASK  221184
#define OFF_GN    258048     // 128: s1[64], s2[64]
#define OFF_STATS 258176     // 64
#define OFF_MAP   258240     // 256 ints: D-layout map[lane*4+reg] = (m<<4)|n
#define OFF_PAIR  258496     // 32 ints: B-slot j holds channel pairB[j]
#define OFF_POS   258528     // 32 ints: posB[c] (kept for reference)

__device__ __forceinline__ ushort f2bf(float f) {
    union { float f; uint u; } v; v.f = f;
    uint r = v.u + 0x7fffu + ((v.u >> 16) & 1u);   // RNE to bf16
    return (ushort)(r >> 16);
}
__device__ __forceinline__ float bf2f(ushort h) {
    union { uint u; float f; } v; v.u = ((uint)h) << 16;
    return v.f;
}

// ------------------------------------------------- prep: wsplit + zero + probes
// All blocks: W hi/lo split into A-frag identity order (r7-proven indexing).
// Block 0 wave 0: D-layout probe. Block 1 wave 0: A/B pairing probe. Block 0: zero GN.
__global__ __launch_bounds__(256) void prep(const float* __restrict__ wd,
                                            ushort* __restrict__ wah,
                                            ushort* __restrict__ wal,
                                            float* __restrict__ gn_part,
                                            int* __restrict__ map,
                                            int* __restrict__ pairB,
                                            int* __restrict__ posB) {
    int b = blockIdx.x, t = threadIdx.x;
    int i = b * 256 + t;                          // < 147456
    {
        int e  = i & 7;
        int l  = (i >> 3) & 63;
        int ot = (i >> 9) & 7;
        int q  = (i >> 12) & 3;
        int k  = i >> 14;                         // 0..8
        int o  = ot * 16 + (l & 15);
        int c  = q * 32 + (l >> 4) * 8 + e;
        float w = wd[o * KDIM + c * KW + k];
        ushort h = f2bf(w);
        wah[i] = h;
        wal[i] = f2bf(w - bf2f(h));
    }
    if (b == 0 && t < 128) gn_part[t] = 0.f;
    if (b == 0 && t < 64) {
        // D-layout probe (HW-verified r4/r6)
        int l = t;
        bf16x8 A1 = {}, B1 = {}, A2 = {}, B2 = {};
        if ((l >> 4) == 0) {
            A1[0] = (short)f2bf((float)((l & 15) + 1));
            B1[0] = (short)f2bf(1.0f);
            A2[0] = (short)f2bf(1.0f);
            B2[0] = (short)f2bf((float)((l & 15) + 1));
        }
        f32x4 d1 = {0.f,0.f,0.f,0.f}, d2 = {0.f,0.f,0.f,0.f};
        d1 = __builtin_amdgcn_mfma_f32_16x16x32_bf16(A1, B1, d1, 0, 0, 0);
        d2 = __builtin_amdgcn_mfma_f32_16x16x32_bf16(A2, B2, d2, 0, 0, 0);
#pragma unroll
        for (int r = 0; r < 4; ++r) {
            int m = (int)(d1[r] + 0.5f) - 1;
            int n = (int)(d2[r] + 0.5f) - 1;
            map[l * 4 + r] = (m << 4) | n;
        }
    }
    if (b == 1 && t < 64) {
        // A/B k-slot pairing probe (HW-verified r6): pairB[j]=s, posB[s]=j
        int l = t;
        union { bf16x8 v; short a[8]; } B;
#pragma unroll
        for (int e = 0; e < 8; ++e) {
            float val = (float)(1u << (((l >> 4) * 8 + e) & 31));
            B.a[e] = (short)f2bf(val);
        }
#pragma unroll
        for (int s = 0; s < 32; ++s) {
            union { bf16x8 v; short a[8]; } A;
#pragma unroll
            for (int e = 0; e < 8; ++e) A.a[e] = 0;
            if ((l >> 4) == (s >> 3)) A.a[s & 7] = (short)f2bf(1.0f);
            f32x4 d = {0.f, 0.f, 0.f, 0.f};
            d = __builtin_amdgcn_mfma_f32_16x16x32_bf16(A.v, B.v, d, 0, 0, 0);
            float v0 = d[0];
            if (l == 0 && v0 > 0.f) {
                int ex; frexpf(v0, &ex);         // v0 = 2^j -> ex = j+1
                int j = ex - 1;
                if (j >= 0 && j < 32) { pairB[j] = s; posB[s] = j; }
            }
        }
    }
}

// ---------------------------------------------------------------- head conv
// 576 blocks: 64 px x 4 channel-groups of 32, LDS reduce (4x parallelism vs r2).
__global__ __launch_bounds__(256) void head_kernel(const float* __restrict__ x,
                                                   const float* __restrict__ w_head,
                                                   const float* __restrict__ b_head,
                                                   float* __restrict__ dxv,
                                                   float* __restrict__ dyv,
                                                   float* __restrict__ maskv) {
    __shared__ float wl[3456];          // wl[(c*9+kk)*3 + j]
    __shared__ float sp[4][64][3];
    int t = threadIdx.x;
    for (int i = t; i < 3456; i += 256) {
        int j = i / KDIM, r = i - j * KDIM;       // i = j*1152 + (c*9+kk)
        wl[r * 3 + j] = w_head[i];
    }
    __syncthreads();

    int lane = t & 63, cg = t >> 6;
    int p = blockIdx.x * 64 + lane;
    int n = p / HWN, hw = p % HWN;
    int h = hw / WW, w = hw % WW;

    int   offs[9];
    float msk[9];
#pragma unroll
    for (int ky = 0; ky < 3; ky++)
#pragma unroll
        for (int kx = 0; kx < 3; kx++) {
            int yy = h - 1 + ky, xx = w - 1 + kx;
            bool ok = (yy >= 0) && (yy < HH) && (xx >= 0) && (xx < WW);
            int yc = min(max(yy, 0), HH - 1), xc = min(max(xx, 0), WW - 1);
            offs[ky * 3 + kx] = yc * WW + xc;
            msk[ky * 3 + kx] = ok ? 1.f : 0.f;
        }

    float a0 = 0.f, a1 = 0.f, a2 = 0.f;
    const float* xn = x + (size_t)n * CIN * HWN;
    for (int c = cg * 32; c < cg * 32 + 32; c++) {
        const float* xc = xn + c * HWN;
        const float* wc = &wl[c * 27];
#pragma unroll
        for (int kk = 0; kk < 9; kk++) {
            float v = xc[offs[kk]] * msk[kk];
            a0 = fmaf(v, wc[kk * 3 + 0], a0);
            a1 = fmaf(v, wc[kk * 3 + 1], a1);
            a2 = fmaf(v, wc[kk * 3 + 2], a2);
        }
    }
    sp[cg][lane][0] = a0; sp[cg][lane][1] = a1; sp[cg][lane][2] = a2;
    __syncthreads();
    if (t < 64) {
        float b0 = sp[0][t][0] + sp[1][t][0] + sp[2][t][0] + sp[3][t][0] + b_head[0];
        float b1 = sp[0][t][1] + sp[1][t][1] + sp[2][t][1] + sp[3][t][1] + b_head[1];
        float b2 = sp[0][t][2] + sp[1][t][2] + sp[2][t][2] + sp[3][t][2] + b_head[2];
        int pp = blockIdx.x * 64 + t;
        dxv[pp]   = 0.25f * tanhf(b0);
        dyv[pp]   = 0.25f * tanhf(b1);
        maskv[pp] = 1.f / (1.f + expf(-b2));
    }
}

// ---------------------------------------------------------------- main DCN
// Block: 128 o x 32 px, 4 waves (1152 blocks -> 18 waves/CU). Thread (pix=t&31,
// sg=t>>5) samples channels pairB[sg*4+e] and writes contiguous short4 into
// fragment-major B tiles (conflict-free). Tap-specialized corner counts:
// taps 0,4 -> 1 gather; 1,2,3,5 -> 2; 6,7,8 -> 4. Double-buffered sB,
// 1 barrier/chunk. A frags global (L2), hi/lo bf16 split (3 MFMAs/pair).
__global__ __launch_bounds__(256) void dcn_kernel(const float* __restrict__ x,
                                                  const ushort* __restrict__ wah,
                                                  const ushort* __restrict__ wal,
                                                  const float* __restrict__ dxv,
                                                  const float* __restrict__ dyv,
                                                  const float* __restrict__ maskv,
                                                  const int* __restrict__ map,
                                                  const int* __restrict__ pairB,
                                                  float* __restrict__ out,
                                                  float* __restrict__ gn_part) {
    __shared__ __attribute__((aligned(16))) ushort sBh[2][4 * PXB * 8];  // 4 KB
    __shared__ __attribute__((aligned(16))) ushort sBl[2][4 * PXB * 8];  // 4 KB
    __shared__ float sMask[PXB];
    __shared__ float gred[16];

    const int t = threadIdx.x;
    const int lane = t & 63;
    const int wv = t >> 6;
    const int lg = lane >> 4;
    const int ml = lane & 15;
    const int pix = t & 31;
    const int sg  = t >> 5;         // 0..7: slot quad sg*4..sg*4+3

    // XCD swizzle: each XCD owns a contiguous half-image slab (L2-resident x)
    int b = blockIdx.x;
    int nb = (b & 7) * (NBLK / 8) + (b >> 3);
    const int p0  = nb * PXB;
    const int n   = p0 / HWN;
    const int hw0 = p0 % HWN;
    const float* xn = x + (size_t)n * CIN * HWN;

    if (t < PXB) sMask[t] = maskv[p0 + t];
    if (t < 16) gred[t] = 0.f;

    const float dxl = dxv[p0 + pix];
    const float dyl = dyv[p0 + pix];
    const int hme = (hw0 + pix) / WW;
    const int wme = (hw0 + pix) % WW;

    int chn[4];
#pragma unroll
    for (int e = 0; e < 4; ++e) chn[e] = pairB[sg * 4 + e] & 31;

    f32x4 acc[2][2];
#pragma unroll
    for (int i = 0; i < 2; i++)
#pragma unroll
        for (int j = 0; j < 2; j++) acc[i][j] = (f32x4){0.f, 0.f, 0.f, 0.f};

    const int oyc[9] = {0, 0, 0, 1, 0, -1, 1, 1, -1};
    const int oxc[9] = {0, 1, -1, 0, 0, 0, 1, -1, 1};
    const int ncl[9] = {1, 2, 2, 2, 1, 2, 4, 4, 4};

#pragma unroll
    for (int k = 0; k < 9; ++k) {
        // ---- per-thread corner setup (registers, no LDS, no barrier)
        const int ky = k / 3, kx = k - ky * 3;
        float py = (float)(hme - 1 + ky) + (float)oyc[k] * dxl;
        float px = (float)(wme - 1 + kx) + (float)oxc[k] * dyl;
        float fy0 = floorf(py), fx0 = floorf(px);
        int y0 = (int)fy0, x0 = (int)fx0;
        float fy = py - fy0, fx = px - fx0;
        int aa[4]; float wq[4];
#pragma unroll
        for (int j = 0; j < 4; ++j) {
            int yy = y0 + (j >> 1), xx = x0 + (j & 1);
            float wb = ((j >> 1) ? fy : 1.f - fy) * ((j & 1) ? fx : 1.f - fx);
            bool ok = (yy >= 0) && (yy < HH) && (xx >= 0) && (xx < WW);
            aa[j] = min(max(yy, 0), HH - 1) * WW + min(max(xx, 0), WW - 1);
            wq[j] = ok ? wb : 0.f;
        }
        if (ncl[k] == 2 && oxc[k] == 0) { aa[1] = aa[2]; wq[1] = wq[2]; }  // integer-px taps
        const int NC = ncl[k];

#pragma unroll
        for (int q = 0; q < 4; ++q) {
            const int cc = q * 32;
            ushort* bufh = sBh[q & 1];
            ushort* bufl = sBl[q & 1];
            // ---- sample 4 channels (all loads independent -> deep in flight)
            float sv[4];
#pragma unroll
            for (int e = 0; e < 4; ++e) {
                const float* xc = xn + (size_t)(cc + chn[e]) * HWN;
                float a0 = xc[aa[0]] * wq[0];
                if (NC >= 2) a0 += xc[aa[1]] * wq[1];
                if (NC == 4) a0 += xc[aa[2]] * wq[2] + xc[aa[3]] * wq[3];
                sv[e] = a0;
            }
            union { short4 v; ushort u[4]; } hv, lv;
#pragma unroll
            for (int e = 0; e < 4; ++e) {
                ushort hh = f2bf(sv[e]);
                hv.u[e] = hh;
                lv.u[e] = f2bf(sv[e] - bf2f(hh));
            }
            const int wbase = ((sg >> 1) * PXB + pix) * 8 + (sg & 1) * 4;
            *(short4*)&bufh[wbase] = hv.v;
            *(short4*)&bufl[wbase] = lv.v;
            // ---- A fragments from global (L2-resident, identity slot order)
            const size_t abase = (size_t)((k * 4 + q) * 8 + wv * 2) * 512 + lane * 8;
            bf16x8 Ah0 = *(const bf16x8*)(wah + abase);
            bf16x8 Ah1 = *(const bf16x8*)(wah + abase + 512);
            bf16x8 Al0 = *(const bf16x8*)(wal + abase);
            bf16x8 Al1 = *(const bf16x8*)(wal + abase + 512);
            __syncthreads();   // sB ready (double buffer -> 1 barrier/chunk)
            // ---- B frags (ds_read_b128) + 12 MFMAs
#pragma unroll
            for (int pt = 0; pt < 2; ++pt) {
                const int rbase = (lg * PXB + pt * 16 + ml) * 8;
                bf16x8 Bh = *(const bf16x8*)&bufh[rbase];
                bf16x8 Bl = *(const bf16x8*)&bufl[rbase];
                acc[0][pt] = __builtin_amdgcn_mfma_f32_16x16x32_bf16(Ah0, Bh, acc[0][pt], 0, 0, 0);
                acc[0][pt] = __builtin_amdgcn_mfma_f32_16x16x32_bf16(Ah0, Bl, acc[0][pt], 0, 0, 0);
                acc[0][pt] = __builtin_amdgcn_mfma_f32_16x16x32_bf16(Al0, Bh, acc[0][pt], 0, 0, 0);
                acc[1][pt] = __builtin_amdgcn_mfma_f32_16x16x32_bf16(Ah1, Bh, acc[1][pt], 0, 0, 0);
                acc[1][pt] = __builtin_amdgcn_mfma_f32_16x16x32_bf16(Ah1, Bl, acc[1][pt], 0, 0, 0);
                acc[1][pt] = __builtin_amdgcn_mfma_f32_16x16x32_bf16(Al1, Bh, acc[1][pt], 0, 0, 0);
            }
        }
    }

    // ---- epilogue: mask, scatter via probed D layout, GN partials
    int4 mn4 = *(const int4*)&map[lane * 4];
    int mn[4] = {mn4.x, mn4.y, mn4.z, mn4.w};
    float s1g[2] = {0.f, 0.f}, s2g[2] = {0.f, 0.f};
#pragma unroll
    for (int ot = 0; ot < 2; ++ot) {
        int otile = wv * 32 + ot * 16;
#pragma unroll
        for (int pt = 0; pt < 2; ++pt) {
#pragma unroll
            for (int r = 0; r < 4; ++r) {
                int m = mn[r] >> 4, nn2 = mn[r] & 15;
                int p = pt * 16 + nn2;
                float v = acc[ot][pt][r] * sMask[p];
                s1g[ot] += v;
                s2g[ot] += v * v;
                out[((size_t)n * COUT + otile + m) * HWN + hw0 + p] = v;
            }
        }
    }
#pragma unroll
    for (int ot = 0; ot < 2; ++ot) {
        int g = wv * 2 + ot;
        atomicAdd(&gred[g * 2 + 0], s1g[ot]);
        atomicAdd(&gred[g * 2 + 1], s2g[ot]);
    }
    __syncthreads();
    if (t < 8) {
        atomicAdd(&gn_part[n * 8 + t],      gred[t * 2 + 0]);
        atomicAdd(&gn_part[64 + n * 8 + t], gred[t * 2 + 1]);
    }
}

// ---------------------------------------------------------------- GN stats
__global__ void gn_stats(const float* __restrict__ gn_part, float* __restrict__ stats) {
    int i = threadIdx.x;
    if (i < 32) {
        float cnt = (float)GSZ * (float)HWN;
        float s1 = gn_part[i], s2 = gn_part[64 + i];
        float mu = s1 / cnt;
        float var = s2 / cnt - mu * mu;
        stats[i] = mu;
        stats[32 + i] = rsqrtf(var + 1e-5f);
    }
}

// ---------------------------------------------------------------- GN apply
__global__ __launch_bounds__(256) void gn_apply(float* __restrict__ out,
                                                const float* __restrict__ stats,
                                                const float* __restrict__ gamma,
                                                const float* __restrict__ beta) {
    int i4 = blockIdx.x * 256 + threadIdx.x;
    size_t e = (size_t)i4 * 4;
    int og = (int)(e / HWN);
    int n = og >> 7, o = og & 127;
    int s = n * 8 + (o >> 4);
    float mu = stats[s], inv = stats[32 + s];
    float ga = gamma[o] * inv;
    float be = beta[o] - mu * ga;
    float4 v = *(float4*)(out + e);
    v.x = fmaxf(fmaf(v.x, ga, be), 0.f);
    v.y = fmaxf(fmaf(v.y, ga, be), 0.f);
    v.z = fmaxf(fmaf(v.z, ga, be), 0.f);
    v.w = fmaxf(fmaf(v.w, ga, be), 0.f);
    *(float4*)(out + e) = v;
}

// ---------------------------------------------------------------- launch
extern "C" void kernel_launch(void* const* d_in, const int* in_sizes, int n_in,
                              void* d_out, int out_size, void* d_ws, size_t ws_size,
                              hipStream_t stream) {
    const float* x       = (const float*)d_in[0];
    const float* w_head  = (const float*)d_in[1];
    const float* b_head  = (const float*)d_in[2];
    const float* w_dcn   = (const float*)d_in[3];
    const float* gamma   = (const float*)d_in[4];
    const float* beta    = (const float*)d_in[5];
    float* out = (float*)d_out;
    float* ws  = (float*)d_ws;

    ushort* wah    = (ushort*)(ws + OFF_WAH);
    ushort* wal    = (ushort*)(ws + OFF_WAL);
    float* dxv     = ws + OFF_DX;
    float* dyv     = ws + OFF_DY;
    float* maskv   = ws + OFF_MASK;
    float* gn_part = ws + OFF_GN;
    float* stats   = ws + OFF_STATS;
    int*   map     = (int*)(ws + OFF_MAP);
    int*   pairB   = (int*)(ws + OFF_PAIR);
    int*   posB    = (int*)(ws + OFF_POS);

    prep<<<147456 / 256, 256, 0, stream>>>(w_dcn, wah, wal, gn_part, map, pairB, posB);
    head_kernel<<<NHW / 64, 256, 0, stream>>>(x, w_head, b_head, dxv, dyv, maskv);
    dcn_kernel<<<NBLK, 256, 0, stream>>>(x, wah, wal, dxv, dyv, maskv, map, pairB, out, gn_part);
    gn_stats<<<1, 64, 0, stream>>>(gn_part, stats);
    gn_apply<<<(NB * COUT * HWN) / 4 / 256, 256, 0, stream>>>(out, stats, gamma, beta);
}